// Round 2
// baseline (55.975 us; speedup 1.0000x reference)
//
#include <hip/hip_runtime.h>

// out[b,c,di,dj] = (1/L) * clamped_boxsum_31x31(x)[di,dj] - center_patch
//   boxsum over rows [di-15, di+15] ∩ [0,30], cols [dj-15, dj+15] ∩ [0,30]
//   center_patch[di,dj] = x[ci+di-15, cj+dj-15] if in bounds else 0,
//   (ci,cj) = divmod(center_idx, 31)
// One block per (b,c) image; separable box-sum via row/col prefix sums in LDS.

#define KS 31
#define PAD 15
#define LL 961  // KS*KS

__global__ __launch_bounds__(1024) void
IrregularDirectionalGradientConv_34144990003267_kernel(const float* __restrict__ x,
                                                       const int* __restrict__ cidx,
                                                       float* __restrict__ out) {
    __shared__ float xs[KS][KS + 1];      // image
    __shared__ float rp[KS][KS + 2];      // row prefix sums, rp[r][j+1] = sum x[r][0..j]
    __shared__ float rs[KS][KS + 1];      // clamped row window sums
    __shared__ float cp[KS + 2][KS + 1];  // column prefix of rs

    const int bc = blockIdx.x;                 // 0..255 = b*32 + c
    const float* __restrict__ img = x + (size_t)bc * LL;
    float* __restrict__ o = out + (size_t)bc * LL;

    const int tid = threadIdx.x;
    const int r = tid / KS;
    const int c = tid - r * KS;

    if (tid < LL) xs[r][c] = img[tid];
    __syncthreads();

    // Row prefix sums: one thread per row (serial 31 adds, trivially cheap).
    if (tid < KS) {
        float s = 0.f;
        rp[tid][0] = 0.f;
#pragma unroll
        for (int j = 0; j < KS; ++j) { s += xs[tid][j]; rp[tid][j + 1] = s; }
    }
    __syncthreads();

    // Clamped horizontal window sum per element.
    if (tid < LL) {
        int lo = c - PAD; if (lo < 0) lo = 0;
        int hi = c + PAD; if (hi > KS - 1) hi = KS - 1;
        rs[r][c] = rp[r][hi + 1] - rp[r][lo];
    }
    __syncthreads();

    // Column prefix sums: one thread per column (threads hit distinct banks).
    if (tid < KS) {
        float s = 0.f;
        cp[0][tid] = 0.f;
#pragma unroll
        for (int i = 0; i < KS; ++i) { s += rs[i][tid]; cp[i + 1][tid] = s; }
    }
    __syncthreads();

    if (tid < LL) {
        int lo = r - PAD; if (lo < 0) lo = 0;
        int hi = r + PAD; if (hi > KS - 1) hi = KS - 1;
        float ws = cp[hi + 1][c] - cp[lo][c];

        const int ci = cidx[0] / KS;
        const int cj = cidx[0] - ci * KS;
        const int rr = ci + r - PAD;
        const int cc = cj + c - PAD;
        const float cen = (rr >= 0 && rr < KS && cc >= 0 && cc < KS) ? xs[rr][cc] : 0.f;

        o[tid] = ws * (1.0f / (float)LL) - cen;
    }
}

extern "C" void kernel_launch(void* const* d_in, const int* in_sizes, int n_in,
                              void* d_out, int out_size, void* d_ws, size_t ws_size,
                              hipStream_t stream) {
    const float* x = (const float*)d_in[0];
    const int* cidx = (const int*)d_in[1];
    float* out = (float*)d_out;
    // B*C = 8*32 = 256 images of 31x31.
    IrregularDirectionalGradientConv_34144990003267_kernel<<<256, 1024, 0, stream>>>(x, cidx, out);
}